// Round 1
// baseline (205.580 us; speedup 1.0000x reference)
//
#include <hip/hip_runtime.h>

// N = 8192 rows, D = 512 features.
// loss = mean((1-cos)^2) over all pairs (margin=1 makes labels irrelevant:
//        max(1-cos,0)^2 == (1-cos)^2 since cos <= 1).
// N^2*loss = N^2 - 2*||s||^2 + ||Xn^T Xn||_F^2,  s_a = sum_i xn[i][a].

typedef __attribute__((ext_vector_type(8))) short  s8;      // 8 bf16 payload (4 VGPR)
typedef __attribute__((ext_vector_type(8))) __bf16 bf8;     // mfma operand type
typedef __attribute__((ext_vector_type(4))) float  f4;

#define KSPLIT 8
#define KC     (8192 / KSPLIT)   // 1024 K per gram block

// ws layout (bytes)
#define OFF_XT 0u                               // bf16 xt[512][8192] = 8 MiB
#define OFF_GP (8u * 1024u * 1024u)             // f32 gp[8][512][512] = 8 MiB
#define OFF_S  (OFF_GP + 8u * 512u * 512u * 4u) // f32 s[512]
#define OFF_S2 (OFF_S + 512u * 4u)              // f32 s2[1]

__device__ __forceinline__ unsigned short f2bf(float f) {
    union { float f; unsigned u; } v; v.f = f;
    unsigned r = v.u + 0x7FFFu + ((v.u >> 16) & 1u);   // RNE
    return (unsigned short)(r >> 16);
}

__global__ __launch_bounds__(576) void k_zero(float* __restrict__ p) {
    if (threadIdx.x < 513) p[threadIdx.x] = 0.f;
}

// --- K1: normalize rows, accumulate s, write transposed bf16 xt[a][i] ---
__global__ __launch_bounds__(512) void k_norm_transpose(
    const float* __restrict__ reps, unsigned short* __restrict__ xt,
    float* __restrict__ svec)
{
    __shared__ unsigned short tile[32][520];   // 520 = 512 + pad (bank spread)
    const int t = threadIdx.x;
    const int w = t >> 6, lane = t & 63;
    const int i0 = blockIdx.x * 64;
    float sacc[8] = {0.f,0.f,0.f,0.f,0.f,0.f,0.f,0.f};

    for (int h = 0; h < 2; ++h) {
        const int ibase = i0 + h * 32;
        // phase 1: each wave normalizes 4 rows into LDS
        for (int rr = 0; rr < 4; ++rr) {
            const int il = w * 4 + rr;
            const int i  = ibase + il;
            const float4 x0 = *(const float4*)(reps + (size_t)i * 512 + lane * 4);
            const float4 x1 = *(const float4*)(reps + (size_t)i * 512 + 256 + lane * 4);
            float ss = x0.x*x0.x + x0.y*x0.y + x0.z*x0.z + x0.w*x0.w
                     + x1.x*x1.x + x1.y*x1.y + x1.z*x1.z + x1.w*x1.w;
            #pragma unroll
            for (int off = 1; off < 64; off <<= 1) ss += __shfl_xor(ss, off, 64);
            const float inv = 1.0f / fmaxf(sqrtf(ss), 1e-8f);
            float xn[8] = {x0.x*inv, x0.y*inv, x0.z*inv, x0.w*inv,
                           x1.x*inv, x1.y*inv, x1.z*inv, x1.w*inv};
            #pragma unroll
            for (int u = 0; u < 8; ++u) sacc[u] += xn[u];
            ushort4 p0, p1;
            p0.x = f2bf(xn[0]); p0.y = f2bf(xn[1]); p0.z = f2bf(xn[2]); p0.w = f2bf(xn[3]);
            p1.x = f2bf(xn[4]); p1.y = f2bf(xn[5]); p1.z = f2bf(xn[6]); p1.w = f2bf(xn[7]);
            *(ushort4*)&tile[il][lane * 4]       = p0;
            *(ushort4*)&tile[il][256 + lane * 4] = p1;
        }
        __syncthreads();
        // phase 2: 4x8 register sub-tile transpose -> coalesced xt writes
        const int si4 = t & 7;     // i-group: rows si4*4 + r
        const int sa  = t >> 3;    // a-group: cols sa*8 + j
        s8 rows[4];
        #pragma unroll
        for (int r = 0; r < 4; ++r)
            rows[r] = *(const s8*)&tile[si4 * 4 + r][sa * 8];
        #pragma unroll
        for (int j = 0; j < 8; ++j) {
            ushort4 o;
            o.x = (unsigned short)rows[0][j];
            o.y = (unsigned short)rows[1][j];
            o.z = (unsigned short)rows[2][j];
            o.w = (unsigned short)rows[3][j];
            *(ushort4*)(xt + (size_t)(sa * 8 + j) * 8192 + ibase + si4 * 4) = o;
        }
        __syncthreads();
    }
    #pragma unroll
    for (int u = 0; u < 4; ++u) {
        atomicAdd(&svec[lane * 4 + u],       sacc[u]);
        atomicAdd(&svec[256 + lane * 4 + u], sacc[4 + u]);
    }
}

// --- K2: G partial = Xn^T Xn over a K-chunk; 1 wave = 64x64 tile, no LDS ---
__global__ __launch_bounds__(64) void k_gram(
    const unsigned short* __restrict__ xt, float* __restrict__ gp)
{
    const int lane = threadIdx.x;
    const int l15 = lane & 15, l4 = lane >> 4;
    const int a0 = blockIdx.y * 64, b0 = blockIdx.x * 64;
    const int k0 = blockIdx.z * KC;
    const unsigned short* Arow = xt + (size_t)(a0 + l15) * 8192;
    const unsigned short* Brow = xt + (size_t)(b0 + l15) * 8192;

    f4 acc[4][4];
    #pragma unroll
    for (int mi = 0; mi < 4; ++mi)
        #pragma unroll
        for (int ni = 0; ni < 4; ++ni) {
            f4 z = {0.f, 0.f, 0.f, 0.f};
            acc[mi][ni] = z;
        }

    for (int k = 0; k < KC; k += 32) {
        const int ko = k0 + k + l4 * 8;
        s8 af[4], bfr[4];
        #pragma unroll
        for (int mi = 0; mi < 4; ++mi)
            af[mi] = *(const s8*)(Arow + (size_t)mi * 16 * 8192 + ko);
        #pragma unroll
        for (int ni = 0; ni < 4; ++ni)
            bfr[ni] = *(const s8*)(Brow + (size_t)ni * 16 * 8192 + ko);
        #pragma unroll
        for (int mi = 0; mi < 4; ++mi)
            #pragma unroll
            for (int ni = 0; ni < 4; ++ni)
                acc[mi][ni] = __builtin_amdgcn_mfma_f32_16x16x32_bf16(
                    __builtin_bit_cast(bf8, af[mi]),
                    __builtin_bit_cast(bf8, bfr[ni]),
                    acc[mi][ni], 0, 0, 0);
    }

    float* gb = gp + (size_t)blockIdx.z * (512 * 512);
    #pragma unroll
    for (int mi = 0; mi < 4; ++mi)
        #pragma unroll
        for (int ni = 0; ni < 4; ++ni)
            #pragma unroll
            for (int r = 0; r < 4; ++r) {
                const int a_ = a0 + mi * 16 + l4 * 4 + r;   // C/D: row=(l>>4)*4+r
                const int b_ = b0 + ni * 16 + l15;          //      col=l&15
                gb[a_ * 512 + b_] = acc[mi][ni][r];
            }
}

// --- K3: S2 = sum over cells of (sum of KSPLIT partials)^2 ---
__global__ __launch_bounds__(256) void k_reduce(
    const float* __restrict__ gp, float* __restrict__ s2)
{
    const int tid = blockIdx.x * 256 + threadIdx.x;   // 512*256 = 131072 threads
    float sq = 0.f;
    for (int c = tid; c < 512 * 512; c += 131072) {
        float sum = 0.f;
        #pragma unroll
        for (int p = 0; p < KSPLIT; ++p) sum += gp[(size_t)p * (512 * 512) + c];
        sq += sum * sum;
    }
    #pragma unroll
    for (int off = 1; off < 64; off <<= 1) sq += __shfl_xor(sq, off, 64);
    __shared__ float part[4];
    if ((threadIdx.x & 63) == 0) part[threadIdx.x >> 6] = sq;
    __syncthreads();
    if (threadIdx.x == 0) atomicAdd(s2, part[0] + part[1] + part[2] + part[3]);
}

// --- K4: loss = (N^2 - 2*||s||^2 + S2) / N^2 ---
__global__ __launch_bounds__(512) void k_final(
    const float* __restrict__ svec, const float* __restrict__ s2,
    float* __restrict__ out)
{
    const int t = threadIdx.x;
    float v = svec[t];
    float p = v * v;
    #pragma unroll
    for (int off = 1; off < 64; off <<= 1) p += __shfl_xor(p, off, 64);
    __shared__ float part[8];
    if ((t & 63) == 0) part[t >> 6] = p;
    __syncthreads();
    if (t == 0) {
        float s1 = 0.f;
        #pragma unroll
        for (int q = 0; q < 8; ++q) s1 += part[q];
        const double NN = 67108864.0;  // 8192^2
        double loss = (NN - 2.0 * (double)s1 + (double)(*s2)) / NN;
        out[0] = (float)loss;
    }
}

extern "C" void kernel_launch(void* const* d_in, const int* in_sizes, int n_in,
                              void* d_out, int out_size, void* d_ws, size_t ws_size,
                              hipStream_t stream)
{
    const float* reps = (const float*)d_in[0];
    // d_in[1] (labels) is mathematically irrelevant for margin = 1.0.
    char* ws = (char*)d_ws;
    unsigned short* xt   = (unsigned short*)(ws + OFF_XT);
    float*          gp   = (float*)(ws + OFF_GP);
    float*          svec = (float*)(ws + OFF_S);
    float*          s2   = (float*)(ws + OFF_S2);

    k_zero<<<1, 576, 0, stream>>>(svec);                         // zeros s[512] + s2
    k_norm_transpose<<<128, 512, 0, stream>>>(reps, xt, svec);
    k_gram<<<dim3(8, 8, KSPLIT), 64, 0, stream>>>(xt, gp);
    k_reduce<<<512, 256, 0, stream>>>(gp, s2);
    k_final<<<1, 512, 0, stream>>>(svec, s2, (float*)d_out);
}

// Round 2
// 97.451 us; speedup vs baseline: 2.1096x; 2.1096x over previous
//
#include <hip/hip_runtime.h>

// N = 8192 rows, D = 512 features.
// loss = mean((1-cos)^2) over all pairs (margin=1 makes labels irrelevant:
//        max(1-cos,0)^2 == (1-cos)^2 since cos <= 1).
// N^2*loss = N^2 - 2*||s||^2 + ||Xn^T Xn||_F^2,  s_a = sum_i xn[i][a].
// G = Xn^T Xn is 512x512 symmetric -> compute only 36 upper-triangle 64x64
// tiles, weight off-diagonal tiles by 2 in the Frobenius sum.

typedef __attribute__((ext_vector_type(8))) short  s8;      // 8 bf16 payload
typedef __attribute__((ext_vector_type(8))) __bf16 bf8;     // mfma operand
typedef __attribute__((ext_vector_type(4))) float  f4;
typedef __attribute__((ext_vector_type(4))) unsigned short u4v;

#define NTILE 36                         // 8*9/2 upper-triangle 64x64 tiles
#define PS_F32 (NTILE * 4096)            // f32 per partial plane (147456)

// ws layout (bytes)
#define OFF_XT  0u                               // bf16 xt[512][8192] = 8 MiB
#define OFF_INV (8u * 1024u * 1024u)             // f32 inv[8192] = 32 KiB
#define OFF_S   (OFF_INV + 8192u * 4u)           // f32 s[512]
#define OFF_S2  (OFF_S + 512u * 4u)              // f32 s2[1]
#define OFF_GP  (8u * 1024u * 1024u + 65536u)    // f32 gp[ksplit][NTILE][64][64]

__device__ __forceinline__ unsigned short f2bf(float f) {
    union { float f; unsigned u; } v; v.f = f;
    unsigned r = v.u + 0x7FFFu + ((v.u >> 16) & 1u);   // RNE
    return (unsigned short)(r >> 16);
}

// --- K1a: per-row inv-norms (one wave per row) + zero svec/s2 from block 0 ---
__global__ __launch_bounds__(256) void k_norms(
    const float* __restrict__ reps, float* __restrict__ inv,
    float* __restrict__ zbuf /* svec[512] + s2[1] contiguous */)
{
    const int t = threadIdx.x, lane = t & 63, w = t >> 6;
    if (blockIdx.x == 0) {
        for (int z = t; z < 513; z += 256) zbuf[z] = 0.f;
    }
    const int row = blockIdx.x * 4 + w;
    const float4 x0 = *(const float4*)(reps + (size_t)row * 512 + lane * 4);
    const float4 x1 = *(const float4*)(reps + (size_t)row * 512 + 256 + lane * 4);
    float ss = x0.x*x0.x + x0.y*x0.y + x0.z*x0.z + x0.w*x0.w
             + x1.x*x1.x + x1.y*x1.y + x1.z*x1.z + x1.w*x1.w;
    #pragma unroll
    for (int off = 1; off < 64; off <<= 1) ss += __shfl_xor(ss, off, 64);
    if (lane == 0) inv[row] = 1.0f / fmaxf(sqrtf(ss), 1e-8f);
}

// --- K1b: normalize + bf16 + 64x64 transpose tiles + fused s-vector ---
__global__ __launch_bounds__(256) void k_norm_transpose(
    const float* __restrict__ reps, const float* __restrict__ inv,
    unsigned short* __restrict__ xt, float* __restrict__ svec)
{
    __shared__ unsigned short tile[64][72];     // +8 pad
    __shared__ float sred[4][64];
    const int t = threadIdx.x, lane = t & 63, w = t >> 6;
    const int a0 = blockIdx.x * 64, i0 = blockIdx.y * 64;
    const int colg = t & 15;                    // col group: cols colg*4..+3
    const int ig0  = t >> 4;                    // 0..15

    float4 sa = {0.f, 0.f, 0.f, 0.f};
    #pragma unroll
    for (int j = 0; j < 4; ++j) {
        const int il = ig0 + j * 16;            // wrong coverage? ig0 in 0..15, j*16 -> 0..63, unique
        const float iv = inv[i0 + il];
        const float4 x = *(const float4*)(reps + (size_t)(i0 + il) * 512 + a0 + colg * 4);
        const float4 xn = {x.x * iv, x.y * iv, x.z * iv, x.w * iv};
        sa.x += xn.x; sa.y += xn.y; sa.z += xn.z; sa.w += xn.w;
        ushort4 p;
        p.x = f2bf(xn.x); p.y = f2bf(xn.y); p.z = f2bf(xn.z); p.w = f2bf(xn.w);
        *(ushort4*)&tile[il][colg * 4] = p;
    }
    __syncthreads();

    // register 4x4 sub-block transpose -> coalesced 128B-per-a-row writes
    {
        const int ig = t & 15, ag = t >> 4;
        u4v rows[4];
        #pragma unroll
        for (int r = 0; r < 4; ++r)
            rows[r] = *(const u4v*)&tile[ig * 4 + r][ag * 4];
        #pragma unroll
        for (int j = 0; j < 4; ++j) {
            ushort4 o;
            o.x = (unsigned short)rows[0][j];
            o.y = (unsigned short)rows[1][j];
            o.z = (unsigned short)rows[2][j];
            o.w = (unsigned short)rows[3][j];
            *(ushort4*)(xt + (size_t)(a0 + ag * 4 + j) * 8192 + i0 + ig * 4) = o;
        }
    }

    // s-vector: reduce over the 16 i-groups (4 in-wave via shfl, 4 waves via LDS)
    sa.x += __shfl_xor(sa.x, 16, 64); sa.x += __shfl_xor(sa.x, 32, 64);
    sa.y += __shfl_xor(sa.y, 16, 64); sa.y += __shfl_xor(sa.y, 32, 64);
    sa.z += __shfl_xor(sa.z, 16, 64); sa.z += __shfl_xor(sa.z, 32, 64);
    sa.w += __shfl_xor(sa.w, 16, 64); sa.w += __shfl_xor(sa.w, 32, 64);
    if (lane < 16) {
        sred[w][lane * 4 + 0] = sa.x; sred[w][lane * 4 + 1] = sa.y;
        sred[w][lane * 4 + 2] = sa.z; sred[w][lane * 4 + 3] = sa.w;
    }
    __syncthreads();
    if (t < 64) {
        const float v = sred[0][t] + sred[1][t] + sred[2][t] + sred[3][t];
        atomicAdd(&svec[a0 + t], v);
    }
}

// --- K2: partial Gram, upper-triangle tiles; 1 wave = 64x64 tile, no LDS ---
__global__ __launch_bounds__(64) void k_gram(
    const unsigned short* __restrict__ xt, float* __restrict__ gp, int kc)
{
    const int lane = threadIdx.x;
    const int l15 = lane & 15, l4 = lane >> 4;
    int tt = blockIdx.x, ta = 0;
    while (tt >= 8 - ta) { tt -= 8 - ta; ++ta; }
    const int tb = ta + tt;
    const int a0 = ta * 64, b0 = tb * 64;
    const int k0 = blockIdx.z * kc;
    const unsigned short* Arow = xt + (size_t)(a0 + l15) * 8192;
    const unsigned short* Brow = xt + (size_t)(b0 + l15) * 8192;

    f4 acc[4][4];
    #pragma unroll
    for (int mi = 0; mi < 4; ++mi)
        #pragma unroll
        for (int ni = 0; ni < 4; ++ni) {
            f4 z = {0.f, 0.f, 0.f, 0.f};
            acc[mi][ni] = z;
        }

    for (int k = 0; k < kc; k += 32) {
        const int ko = k0 + k + l4 * 8;
        s8 af[4], bfr[4];
        #pragma unroll
        for (int mi = 0; mi < 4; ++mi)
            af[mi] = *(const s8*)(Arow + (size_t)mi * 16 * 8192 + ko);
        #pragma unroll
        for (int ni = 0; ni < 4; ++ni)
            bfr[ni] = *(const s8*)(Brow + (size_t)ni * 16 * 8192 + ko);
        #pragma unroll
        for (int mi = 0; mi < 4; ++mi)
            #pragma unroll
            for (int ni = 0; ni < 4; ++ni)
                acc[mi][ni] = __builtin_amdgcn_mfma_f32_16x16x32_bf16(
                    __builtin_bit_cast(bf8, af[mi]),
                    __builtin_bit_cast(bf8, bfr[ni]),
                    acc[mi][ni], 0, 0, 0);
    }

    float* gb = gp + (size_t)blockIdx.z * PS_F32 + (size_t)blockIdx.x * 4096;
    #pragma unroll
    for (int mi = 0; mi < 4; ++mi)
        #pragma unroll
        for (int ni = 0; ni < 4; ++ni)
            #pragma unroll
            for (int r = 0; r < 4; ++r) {
                const int a_ = mi * 16 + l4 * 4 + r;   // local row
                const int b_ = ni * 16 + l15;          // local col
                gb[a_ * 64 + b_] = acc[mi][ni][r];
            }
}

// --- K3: S2 = sum of weights * (sum over ksplit partials)^2 ---
__global__ __launch_bounds__(256) void k_reduce(
    const float* __restrict__ gp, float* __restrict__ s2, int ksplit)
{
    const int c = blockIdx.x * 256 + threadIdx.x;   // f4 cell, 36864 total
    const f4* g4 = (const f4*)gp;
    f4 s = {0.f, 0.f, 0.f, 0.f};
    for (int p = 0; p < ksplit; ++p) s += g4[(size_t)p * (PS_F32 / 4) + c];
    int tt = c >> 10, ta = 0;                        // tile index
    while (tt >= 8 - ta) { tt -= 8 - ta; ++ta; }
    const float wgt = (tt == 0) ? 1.f : 2.f;         // diag vs off-diag tile
    float sq = wgt * (s.x * s.x + s.y * s.y + s.z * s.z + s.w * s.w);
    #pragma unroll
    for (int off = 1; off < 64; off <<= 1) sq += __shfl_xor(sq, off, 64);
    __shared__ float part[4];
    if ((threadIdx.x & 63) == 0) part[threadIdx.x >> 6] = sq;
    __syncthreads();
    if (threadIdx.x == 0) atomicAdd(s2, part[0] + part[1] + part[2] + part[3]);
}

// --- K4: loss = (N^2 - 2*||s||^2 + S2) / N^2 ---
__global__ __launch_bounds__(512) void k_final(
    const float* __restrict__ svec, const float* __restrict__ s2,
    float* __restrict__ out)
{
    const int t = threadIdx.x;
    float v = svec[t];
    float p = v * v;
    #pragma unroll
    for (int off = 1; off < 64; off <<= 1) p += __shfl_xor(p, off, 64);
    __shared__ float part[8];
    if ((t & 63) == 0) part[t >> 6] = p;
    __syncthreads();
    if (t == 0) {
        float s1 = 0.f;
        #pragma unroll
        for (int q = 0; q < 8; ++q) s1 += part[q];
        const double NN = 67108864.0;  // 8192^2
        double loss = (NN - 2.0 * (double)s1 + (double)(*s2)) / NN;
        out[0] = (float)loss;
    }
}

extern "C" void kernel_launch(void* const* d_in, const int* in_sizes, int n_in,
                              void* d_out, int out_size, void* d_ws, size_t ws_size,
                              hipStream_t stream)
{
    const float* reps = (const float*)d_in[0];
    // d_in[1] (labels) is mathematically irrelevant for margin = 1.0.
    char* ws = (char*)d_ws;
    unsigned short* xt   = (unsigned short*)(ws + OFF_XT);
    float*          invn = (float*)(ws + OFF_INV);
    float*          svec = (float*)(ws + OFF_S);
    float*          s2   = (float*)(ws + OFF_S2);
    float*          gp   = (float*)(ws + OFF_GP);

    // ksplit: constant given ws_size (same every call -> graph-capture safe)
    const size_t psb = (size_t)PS_F32 * 4;
    int ksplit = 8;
    if (ws_size >= OFF_GP + 32 * psb)      ksplit = 32;
    else if (ws_size >= OFF_GP + 16 * psb) ksplit = 16;
    const int kc = 8192 / ksplit;

    k_norms<<<2048, 256, 0, stream>>>(reps, invn, svec);
    k_norm_transpose<<<dim3(8, 128), 256, 0, stream>>>(reps, invn, xt, svec);
    k_gram<<<dim3(NTILE, 1, ksplit), 64, 0, stream>>>(xt, gp, kc);
    k_reduce<<<144, 256, 0, stream>>>(gp, s2, ksplit);
    k_final<<<1, 512, 0, stream>>>(svec, s2, (float*)d_out);
}